// Round 1
// baseline (2011.584 us; speedup 1.0000x reference)
//
#include <hip/hip_runtime.h>
#include <hip/hip_bf16.h>

// Problem constants (fixed by setup_inputs)
#define H    300
#define KP   320            // K padded to multiple of 32
#define BM   2048           // num molecules
#define SEG  48
#define NTOK (BM*SEG)       // 98304
#define G    900            // 3*H
#define GP   912            // hp width: 57*16
#define NT   57             // GP/16
#define GW   1024           // wih row-pad: 8*128 (B-operand tiles)
#define XPW  912            // xp row stride (cols >= 900 never read; 912 keeps 4B align)
#define MOLW 32             // molecules per recurrent workgroup
#define NPAIR (MOLW*150)    // bf16-pairs of gate state per wg = 4800

typedef __attribute__((ext_vector_type(8))) short short8;
typedef __attribute__((ext_vector_type(4))) float f32x4;

__device__ __forceinline__ float lo16(unsigned u) { return __uint_as_float(u << 16); }
__device__ __forceinline__ float hi16(unsigned u) { return __uint_as_float(u & 0xffff0000u); }
__device__ __forceinline__ unsigned short bfb(float f) {
    __hip_bfloat16 b = __float2bfloat16(f);
    return *(unsigned short*)&b;
}

// ---------------- prep: weights -> padded bf16, biases -> padded f32 ----------------
__global__ void prep_weights(const float* wih_f, const float* whh_f, const float* bih_f,
                             const float* wih_b, const float* whh_b, const float* bih_b,
                             __hip_bfloat16* wih, __hip_bfloat16* whh, float* bih) {
    int idx = blockIdx.x * 256 + threadIdx.x;
    const int wih_n = 2 * GW * KP;
    const int whh_n = 2 * GP * KP;
    if (idx < wih_n) {
        int d = idx / (GW * KP);
        int r = (idx / KP) % GW;
        int k = idx % KP;
        const float* src = d ? wih_b : wih_f;
        float v = (r < G && k < H) ? src[r * H + k] : 0.f;
        wih[idx] = __float2bfloat16(v);
        return;
    }
    idx -= wih_n;
    if (idx < whh_n) {
        int d = idx / (GP * KP);
        int r = (idx / KP) % GP;
        int k = idx % KP;
        const float* src = d ? whh_b : whh_f;
        float v = (r < G && k < H) ? src[r * H + k] : 0.f;
        whh[idx] = __float2bfloat16(v);
        return;
    }
    idx -= whh_n;
    if (idx < 2 * GW) {
        int d = idx / GW;
        int r = idx % GW;
        const float* src = d ? bih_b : bih_f;
        bih[idx] = (r < G) ? src[r] : 0.f;
    }
}

// ---------------- prep: message = bf16(relu(x + bias)), K-padded ----------------
__global__ void prep_msg(const float* x, const float* bias, __hip_bfloat16* msg) {
    int idx = blockIdx.x * 256 + threadIdx.x;      // over NTOK*KP = 31,457,280
    if (idx >= NTOK * KP) return;
    int i = idx / KP, k = idx % KP;
    float v = 0.f;
    if (k < H) {
        v = x[i * H + k] + bias[k];
        v = v > 0.f ? v : 0.f;
    }
    msg[idx] = __float2bfloat16(v);
}

// ---------------- prep: h0 = segment_max(x) ----------------
__global__ void h0_kernel(const float* x, float* h0) {
    int m = blockIdx.x;
    for (int c = threadIdx.x; c < H; c += blockDim.x) {
        const float* base = x + (long long)m * SEG * H + c;
        float v = -INFINITY;
        for (int t = 0; t < SEG; t++) v = fmaxf(v, base[t * H]);
        h0[m * H + c] = v;
    }
}

// ---------------- xp = msg @ w_ih^T + b_ih  (bf16 MFMA, stored bf16, row stride XPW) ----------------
__global__ __launch_bounds__(256) void xp_gemm(const __hip_bfloat16* msg, const __hip_bfloat16* wih,
                                               const float* bih, __hip_bfloat16* xp) {
    int d = blockIdx.z;
    const short* A  = (const short*)msg;
    const short* Bw = (const short*)(wih + d * GW * KP);
    const float* bi = bih + d * GW;
    __hip_bfloat16* out = xp + (long long)d * NTOK * XPW;

    int lane = threadIdx.x & 63;
    int wid  = threadIdx.x >> 6;
    int l15  = lane & 15, quad = lane >> 4;
    int mbase = blockIdx.x * 128 + (wid >> 1) * 64;
    int nbase = blockIdx.y * 128 + (wid & 1) * 64;

    f32x4 acc[4][4] = {};
    for (int kc = 0; kc < KP; kc += 32) {
        int koff = kc + quad * 8;
        short8 a[4], b[4];
#pragma unroll
        for (int i = 0; i < 4; i++)
            a[i] = *(const short8*)(A + (mbase + i * 16 + l15) * KP + koff);
#pragma unroll
        for (int j = 0; j < 4; j++)
            b[j] = *(const short8*)(Bw + (nbase + j * 16 + l15) * KP + koff);
#pragma unroll
        for (int i = 0; i < 4; i++)
#pragma unroll
            for (int j = 0; j < 4; j++)
                acc[i][j] = __builtin_amdgcn_mfma_f32_16x16x32_bf16(a[i], b[j], acc[i][j], 0, 0, 0);
    }
#pragma unroll
    for (int i = 0; i < 4; i++)
#pragma unroll
        for (int j = 0; j < 4; j++) {
            int col = nbase + j * 16 + l15;
            float bv = bi[col];
            if (col < XPW) {
#pragma unroll
                for (int r = 0; r < 4; r++) {
                    int row = mbase + i * 16 + quad * 4 + r;
                    out[(long long)row * XPW + col] = __float2bfloat16(acc[i][j][r] + bv);
                }
            }
        }
}

// ---------------- persistent bidirectional GRU over 48 steps ----------------
// grid (BM/MOLW=64, 2), 512 threads = 8 waves.
__global__ __launch_bounds__(512, 2) void gru_kernel(const __hip_bfloat16* whh_all, const float* bhh_f,
                                                     const float* bhh_b, const __hip_bfloat16* xp,
                                                     const float* h0, float* out) {
    int grp = blockIdx.x;      // molecule group, 0..63
    int d   = blockIdx.y;      // direction
    const short* Ws = (const short*)(whh_all + d * GP * KP);
    const float* bhh = d ? bhh_b : bhh_f;
    const __hip_bfloat16* xpd = xp + (long long)d * NTOK * XPW;

    int tid = threadIdx.x;
    int lane = tid & 63, wid = tid >> 6;           // wid 0..7
    int l15 = lane & 15, quad = lane >> 4;

    __shared__ __hip_bfloat16 hB[MOLW * 328];      // 20,992 B  bf16 h (A-operand), stride 328
    __shared__ __hip_bfloat16 hp[MOLW * GP];       // 58,368 B  recurrent projections (+b_hh)
    const short* hBs = (const short*)hB;

    int mol0 = grp * MOLW;

    // ---- zero hB (incl. K-pad cols 300..327) ----
    for (int e = tid; e < MOLW * 328; e += 512) hB[e] = __float2bfloat16(0.f);

    // ---- hoist bhh per-wave tile biases ----
    float bvw[8];
#pragma unroll
    for (int k = 0; k < 8; k++) {
        int nt = wid + 8 * k;
        int gc = nt * 16 + l15;
        bvw[k] = (nt < NT && gc < G) ? bhh[gc] : 0.f;
    }
    __syncthreads();   // hB zeros visible before pair-writes below

    // ---- init h state: registers (gate-thread ownership) + hB bf16 copy ----
    float hv0[10], hv1[10];
#pragma unroll
    for (int i = 0; i < 10; i++) {
        int e2 = tid + i * 512;
        if (e2 < NPAIR) {
            int m = e2 / 150, c = 2 * (e2 % 150);
            float2 hh = *(const float2*)(h0 + (size_t)(mol0 + m) * H + c);
            hv0[i] = hh.x; hv1[i] = hh.y;
            unsigned pack = ((unsigned)bfb(hh.y) << 16) | bfb(hh.x);
            *(unsigned*)(&hB[m * 328 + c]) = pack;
        }
    }
    __syncthreads();

    for (int t = 0; t < SEG; t++) {
        int tt = d ? (SEG - 1 - t) : t;

        // ---- issue xp prefetch for this step (global, overlaps GEMM) ----
        unsigned pr[10], pz[10], pn[10];
#pragma unroll
        for (int i = 0; i < 10; i++) {
            int e2 = tid + i * 512;
            if (e2 < NPAIR) {
                int m = e2 / 150, c = 2 * (e2 % 150);
                const __hip_bfloat16* xrow = xpd + ((long long)(mol0 + m) * SEG + tt) * XPW;
                pr[i] = *(const unsigned*)(xrow + c);
                pz[i] = *(const unsigned*)(xrow + c + 300);
                pn[i] = *(const unsigned*)(xrow + c + 600);
            }
        }

        // ---- load nt-invariant A-fragments (2 row-blocks of 16 mols) ----
        short8 afA[10], afB[10];
#pragma unroll
        for (int kk = 0; kk < 10; kk++) {
            int koff = kk * 32 + quad * 8;
            afA[kk] = *(const short8*)(hBs + l15 * 328 + koff);
            afB[kk] = *(const short8*)(hBs + (16 + l15) * 328 + koff);
        }

        // ---- GEMM: hp = h @ w_hh^T + b_hh ----
        int k8 = 0;
        for (int nt = wid; nt < NT; nt += 8, k8++) {
            int gcol = nt * 16 + l15;
            const short* bp = Ws + gcol * KP;
            f32x4 acc0 = {0.f, 0.f, 0.f, 0.f};
            f32x4 acc1 = {0.f, 0.f, 0.f, 0.f};
#pragma unroll
            for (int kk = 0; kk < 10; kk++) {
                short8 b = *(const short8*)(bp + kk * 32 + quad * 8);
                acc0 = __builtin_amdgcn_mfma_f32_16x16x32_bf16(afA[kk], b, acc0, 0, 0, 0);
                acc1 = __builtin_amdgcn_mfma_f32_16x16x32_bf16(afB[kk], b, acc1, 0, 0, 0);
            }
            float bv = bvw[k8];
#pragma unroll
            for (int r = 0; r < 4; r++) {
                hp[(quad * 4 + r) * GP + gcol]        = __float2bfloat16(acc0[r] + bv);
                hp[(16 + quad * 4 + r) * GP + gcol]   = __float2bfloat16(acc1[r] + bv);
            }
        }
        __syncthreads();

        // ---- pointwise GRU gates (fp32, 2 elems/thread/iter) ----
#pragma unroll
        for (int i = 0; i < 10; i++) {
            int e2 = tid + i * 512;
            if (e2 < NPAIR) {
                int m = e2 / 150, c = 2 * (e2 % 150);
                unsigned hr2 = *(const unsigned*)(&hp[m * GP + c]);
                unsigned hz2 = *(const unsigned*)(&hp[m * GP + c + 300]);
                unsigned hn2 = *(const unsigned*)(&hp[m * GP + c + 600]);

                float xr0 = lo16(pr[i]), xr1 = hi16(pr[i]);
                float xz0 = lo16(pz[i]), xz1 = hi16(pz[i]);
                float xn0 = lo16(pn[i]), xn1 = hi16(pn[i]);
                float hr0 = lo16(hr2),  hr1 = hi16(hr2);
                float hz0 = lo16(hz2),  hz1 = hi16(hz2);
                float hn0 = lo16(hn2),  hn1 = hi16(hn2);

                float rg0 = 1.f / (1.f + __expf(-(xr0 + hr0)));
                float rg1 = 1.f / (1.f + __expf(-(xr1 + hr1)));
                float zg0 = 1.f / (1.f + __expf(-(xz0 + hz0)));
                float zg1 = 1.f / (1.f + __expf(-(xz1 + hz1)));
                float ni0 = xn0 + rg0 * hn0;
                float ni1 = xn1 + rg1 * hn1;
                float ng0 = 1.f - 2.f / (__expf(2.f * ni0) + 1.f);
                float ng1 = 1.f - 2.f / (__expf(2.f * ni1) + 1.f);
                float h0n = (1.f - zg0) * ng0 + zg0 * hv0[i];
                float h1n = (1.f - zg1) * ng1 + zg1 * hv1[i];
                hv0[i] = h0n; hv1[i] = h1n;

                unsigned pack = ((unsigned)bfb(h1n) << 16) | bfb(h0n);
                *(unsigned*)(&hB[m * 328 + c]) = pack;

                long long tok = (long long)(mol0 + m) * SEG + tt;
                *(float2*)(out + tok * 600 + d * 300 + c) = make_float2(h0n, h1n);
            }
        }
        __syncthreads();
    }
}

extern "C" void kernel_launch(void* const* d_in, const int* in_sizes, int n_in,
                              void* d_out, int out_size, void* d_ws, size_t ws_size,
                              hipStream_t stream) {
    const float* x     = (const float*)d_in[0];
    const float* bias  = (const float*)d_in[4];
    const float* wih_f = (const float*)d_in[5];
    const float* whh_f = (const float*)d_in[6];
    const float* bih_f = (const float*)d_in[7];
    const float* bhh_f = (const float*)d_in[8];
    const float* wih_b = (const float*)d_in[9];
    const float* whh_b = (const float*)d_in[10];
    const float* bih_b = (const float*)d_in[11];
    const float* bhh_b = (const float*)d_in[12];
    float* out = (float*)d_out;

    // Workspace layout (total 426,471,424 B ~= 406.7 MiB; xp shrunk 1024->912 stride
    // to keep well clear of ws_size — previous 448.7 MiB layout was suspected of
    // overrunning the workspace and corrupting an adjacent allocation after replays)
    char* ws = (char*)d_ws;
    __hip_bfloat16* msg = (__hip_bfloat16*)(ws);                    //  62,914,560 B
    __hip_bfloat16* wih = (__hip_bfloat16*)(ws + 62914560LL);       //   1,310,720 B
    __hip_bfloat16* whh = (__hip_bfloat16*)(ws + 64225280LL);       //   1,167,360 B
    float*          bih = (float*)         (ws + 65392640LL);       //       8,192 B
    float*          h0  = (float*)         (ws + 65400832LL);       //   2,457,600 B
    __hip_bfloat16* xp  = (__hip_bfloat16*)(ws + 67858432LL);       // 358,612,992 B

    hipLaunchKernelGGL(prep_weights, dim3((2*GW*KP + 2*GP*KP + 2*GW + 255) / 256), dim3(256), 0, stream,
                       wih_f, whh_f, bih_f, wih_b, whh_b, bih_b, wih, whh, bih);
    hipLaunchKernelGGL(prep_msg, dim3((NTOK * KP + 255) / 256), dim3(256), 0, stream, x, bias, msg);
    hipLaunchKernelGGL(h0_kernel, dim3(BM), dim3(256), 0, stream, x, h0);
    hipLaunchKernelGGL(xp_gemm, dim3(NTOK / 128, GW / 128, 2), dim3(256), 0, stream, msg, wih, bih, xp);
    hipLaunchKernelGGL(gru_kernel, dim3(BM / MOLW, 2), dim3(512), 0, stream, whh, bhh_f, bhh_b, xp, h0, out);
}

// Round 2
// 1733.243 us; speedup vs baseline: 1.1606x; 1.1606x over previous
//
#include <hip/hip_runtime.h>
#include <hip/hip_bf16.h>

// Problem constants (fixed by setup_inputs)
#define H    300
#define KP   320            // K padded to multiple of 32
#define BM   2048           // num molecules
#define SEG  48
#define NTOK (BM*SEG)       // 98304
#define G    900            // 3*H
#define GP   912            // hp width: 57*16
#define NT   57             // GP/16
#define GW   1024           // wih row-pad: 8*128 (B-operand tiles)
#define XPW  912            // xp row stride (cols >= 900 never read; 912 keeps 4B align)
#define MOLW 16             // molecules per recurrent workgroup
#define WGT  1024           // gru workgroup threads (16 waves -> 4 waves/SIMD, 1 WG/CU)
#define NPAIR (MOLW*150)    // bf16-pairs of gate state per wg = 2400
#define PIT  3              // pointwise iters: ceil(NPAIR/WGT)

typedef __attribute__((ext_vector_type(8))) short short8;
typedef __attribute__((ext_vector_type(4))) float f32x4;

__device__ __forceinline__ float lo16(unsigned u) { return __uint_as_float(u << 16); }
__device__ __forceinline__ float hi16(unsigned u) { return __uint_as_float(u & 0xffff0000u); }
__device__ __forceinline__ unsigned short bfb(float f) {
    __hip_bfloat16 b = __float2bfloat16(f);
    return *(unsigned short*)&b;
}

// ---------------- prep: weights -> padded bf16, biases -> padded f32 ----------------
__global__ void prep_weights(const float* wih_f, const float* whh_f, const float* bih_f,
                             const float* wih_b, const float* whh_b, const float* bih_b,
                             __hip_bfloat16* wih, __hip_bfloat16* whh, float* bih) {
    int idx = blockIdx.x * 256 + threadIdx.x;
    const int wih_n = 2 * GW * KP;
    const int whh_n = 2 * GP * KP;
    if (idx < wih_n) {
        int d = idx / (GW * KP);
        int r = (idx / KP) % GW;
        int k = idx % KP;
        const float* src = d ? wih_b : wih_f;
        float v = (r < G && k < H) ? src[r * H + k] : 0.f;
        wih[idx] = __float2bfloat16(v);
        return;
    }
    idx -= wih_n;
    if (idx < whh_n) {
        int d = idx / (GP * KP);
        int r = (idx / KP) % GP;
        int k = idx % KP;
        const float* src = d ? whh_b : whh_f;
        float v = (r < G && k < H) ? src[r * H + k] : 0.f;
        whh[idx] = __float2bfloat16(v);
        return;
    }
    idx -= whh_n;
    if (idx < 2 * GW) {
        int d = idx / GW;
        int r = idx % GW;
        const float* src = d ? bih_b : bih_f;
        bih[idx] = (r < G) ? src[r] : 0.f;
    }
}

// ---------------- prep: message = bf16(relu(x + bias)), K-padded ----------------
__global__ void prep_msg(const float* x, const float* bias, __hip_bfloat16* msg) {
    int idx = blockIdx.x * 256 + threadIdx.x;      // over NTOK*KP = 31,457,280
    if (idx >= NTOK * KP) return;
    int i = idx / KP, k = idx % KP;
    float v = 0.f;
    if (k < H) {
        v = x[i * H + k] + bias[k];
        v = v > 0.f ? v : 0.f;
    }
    msg[idx] = __float2bfloat16(v);
}

// ---------------- prep: h0 = segment_max(x) ----------------
__global__ void h0_kernel(const float* x, float* h0) {
    int m = blockIdx.x;
    for (int c = threadIdx.x; c < H; c += blockDim.x) {
        const float* base = x + (long long)m * SEG * H + c;
        float v = -INFINITY;
        for (int t = 0; t < SEG; t++) v = fmaxf(v, base[t * H]);
        h0[m * H + c] = v;
    }
}

// ---------------- xp = msg @ w_ih^T + b_ih  (bf16 MFMA, stored bf16, row stride XPW) ----------------
__global__ __launch_bounds__(256) void xp_gemm(const __hip_bfloat16* msg, const __hip_bfloat16* wih,
                                               const float* bih, __hip_bfloat16* xp) {
    int d = blockIdx.z;
    const short* A  = (const short*)msg;
    const short* Bw = (const short*)(wih + d * GW * KP);
    const float* bi = bih + d * GW;
    __hip_bfloat16* out = xp + (long long)d * NTOK * XPW;

    int lane = threadIdx.x & 63;
    int wid  = threadIdx.x >> 6;
    int l15  = lane & 15, quad = lane >> 4;
    int mbase = blockIdx.x * 128 + (wid >> 1) * 64;
    int nbase = blockIdx.y * 128 + (wid & 1) * 64;

    f32x4 acc[4][4] = {};
    for (int kc = 0; kc < KP; kc += 32) {
        int koff = kc + quad * 8;
        short8 a[4], b[4];
#pragma unroll
        for (int i = 0; i < 4; i++)
            a[i] = *(const short8*)(A + (mbase + i * 16 + l15) * KP + koff);
#pragma unroll
        for (int j = 0; j < 4; j++)
            b[j] = *(const short8*)(Bw + (nbase + j * 16 + l15) * KP + koff);
#pragma unroll
        for (int i = 0; i < 4; i++)
#pragma unroll
            for (int j = 0; j < 4; j++)
                acc[i][j] = __builtin_amdgcn_mfma_f32_16x16x32_bf16(a[i], b[j], acc[i][j], 0, 0, 0);
    }
#pragma unroll
    for (int i = 0; i < 4; i++)
#pragma unroll
        for (int j = 0; j < 4; j++) {
            int col = nbase + j * 16 + l15;
            float bv = bi[col];
            if (col < XPW) {
#pragma unroll
                for (int r = 0; r < 4; r++) {
                    int row = mbase + i * 16 + quad * 4 + r;
                    out[(long long)row * XPW + col] = __float2bfloat16(acc[i][j][r] + bv);
                }
            }
        }
}

// ---------------- persistent bidirectional GRU over 48 steps ----------------
// grid (BM/MOLW=128, 2) = 256 WGs, 1024 threads = 16 waves -> 1 WG/CU on all 256 CUs,
// 4 waves/SIMD (was: 128 WGs / 2 waves/SIMD -> half the chip idle, latency-bound).
__global__ __launch_bounds__(WGT, 4) void gru_kernel(const __hip_bfloat16* whh_all, const float* bhh_f,
                                                     const float* bhh_b, const __hip_bfloat16* xp,
                                                     const float* h0, float* out) {
    int grp = blockIdx.x;      // molecule group, 0..127
    int d   = blockIdx.y;      // direction
    const short* Ws = (const short*)(whh_all + d * GP * KP);
    const float* bhh = d ? bhh_b : bhh_f;
    const __hip_bfloat16* xpd = xp + (long long)d * NTOK * XPW;

    int tid = threadIdx.x;
    int lane = tid & 63, wid = tid >> 6;           // wid 0..15
    int l15 = lane & 15, quad = lane >> 4;

    __shared__ __hip_bfloat16 hB[MOLW * 328];      // 10,496 B  bf16 h (A-operand), stride 328
    __shared__ __hip_bfloat16 hp[MOLW * GP];       // 29,184 B  recurrent projections (+b_hh)
    const short* hBs = (const short*)hB;

    int mol0 = grp * MOLW;

    // ---- zero hB (incl. K-pad cols 300..327) ----
    for (int e = tid; e < MOLW * 328; e += WGT) hB[e] = __float2bfloat16(0.f);

    // ---- hoist bhh per-wave tile biases (nt = wid + 16k, k<4) ----
    float bvw[4];
#pragma unroll
    for (int k = 0; k < 4; k++) {
        int nt = wid + 16 * k;
        int gc = nt * 16 + l15;
        bvw[k] = (nt < NT && gc < G) ? bhh[gc] : 0.f;
    }
    __syncthreads();   // hB zeros visible before pair-writes below

    // ---- init h state: registers (gate-thread ownership) + hB bf16 copy ----
    float hv0[PIT], hv1[PIT];
#pragma unroll
    for (int i = 0; i < PIT; i++) {
        int e2 = tid + i * WGT;
        if (e2 < NPAIR) {
            int m = e2 / 150, c = 2 * (e2 % 150);
            float2 hh = *(const float2*)(h0 + (size_t)(mol0 + m) * H + c);
            hv0[i] = hh.x; hv1[i] = hh.y;
            unsigned pack = ((unsigned)bfb(hh.y) << 16) | bfb(hh.x);
            *(unsigned*)(&hB[m * 328 + c]) = pack;
        }
    }
    __syncthreads();

    for (int t = 0; t < SEG; t++) {
        int tt = d ? (SEG - 1 - t) : t;

        // ---- issue xp prefetch for this step (global, overlaps GEMM) ----
        unsigned pr[PIT], pz[PIT], pn[PIT];
#pragma unroll
        for (int i = 0; i < PIT; i++) {
            int e2 = tid + i * WGT;
            if (e2 < NPAIR) {
                int m = e2 / 150, c = 2 * (e2 % 150);
                const __hip_bfloat16* xrow = xpd + ((long long)(mol0 + m) * SEG + tt) * XPW;
                pr[i] = *(const unsigned*)(xrow + c);
                pz[i] = *(const unsigned*)(xrow + c + 300);
                pn[i] = *(const unsigned*)(xrow + c + 600);
            }
        }

        // ---- load nt-invariant A-fragments (single 16-row block) ----
        short8 afA[10];
#pragma unroll
        for (int kk = 0; kk < 10; kk++) {
            int koff = kk * 32 + quad * 8;
            afA[kk] = *(const short8*)(hBs + l15 * 328 + koff);
        }

        // ---- GEMM: hp = h @ w_hh^T + b_hh ----
        int k8 = 0;
        for (int nt = wid; nt < NT; nt += 16, k8++) {
            int gcol = nt * 16 + l15;
            const short* bp = Ws + gcol * KP;
            f32x4 acc0 = {0.f, 0.f, 0.f, 0.f};
#pragma unroll
            for (int kk = 0; kk < 10; kk++) {
                short8 b = *(const short8*)(bp + kk * 32 + quad * 8);
                acc0 = __builtin_amdgcn_mfma_f32_16x16x32_bf16(afA[kk], b, acc0, 0, 0, 0);
            }
            float bv = bvw[k8];
#pragma unroll
            for (int r = 0; r < 4; r++)
                hp[(quad * 4 + r) * GP + gcol] = __float2bfloat16(acc0[r] + bv);
        }
        __syncthreads();

        // ---- pointwise GRU gates (fp32, 2 elems/thread/iter) ----
#pragma unroll
        for (int i = 0; i < PIT; i++) {
            int e2 = tid + i * WGT;
            if (e2 < NPAIR) {
                int m = e2 / 150, c = 2 * (e2 % 150);
                unsigned hr2 = *(const unsigned*)(&hp[m * GP + c]);
                unsigned hz2 = *(const unsigned*)(&hp[m * GP + c + 300]);
                unsigned hn2 = *(const unsigned*)(&hp[m * GP + c + 600]);

                float xr0 = lo16(pr[i]), xr1 = hi16(pr[i]);
                float xz0 = lo16(pz[i]), xz1 = hi16(pz[i]);
                float xn0 = lo16(pn[i]), xn1 = hi16(pn[i]);
                float hr0 = lo16(hr2),  hr1 = hi16(hr2);
                float hz0 = lo16(hz2),  hz1 = hi16(hz2);
                float hn0 = lo16(hn2),  hn1 = hi16(hn2);

                float rg0 = 1.f / (1.f + __expf(-(xr0 + hr0)));
                float rg1 = 1.f / (1.f + __expf(-(xr1 + hr1)));
                float zg0 = 1.f / (1.f + __expf(-(xz0 + hz0)));
                float zg1 = 1.f / (1.f + __expf(-(xz1 + hz1)));
                float ni0 = xn0 + rg0 * hn0;
                float ni1 = xn1 + rg1 * hn1;
                float ng0 = 1.f - 2.f / (__expf(2.f * ni0) + 1.f);
                float ng1 = 1.f - 2.f / (__expf(2.f * ni1) + 1.f);
                float h0n = (1.f - zg0) * ng0 + zg0 * hv0[i];
                float h1n = (1.f - zg1) * ng1 + zg1 * hv1[i];
                hv0[i] = h0n; hv1[i] = h1n;

                unsigned pack = ((unsigned)bfb(h1n) << 16) | bfb(h0n);
                *(unsigned*)(&hB[m * 328 + c]) = pack;

                long long tok = (long long)(mol0 + m) * SEG + tt;
                *(float2*)(out + tok * 600 + d * 300 + c) = make_float2(h0n, h1n);
            }
        }
        __syncthreads();
    }
}

extern "C" void kernel_launch(void* const* d_in, const int* in_sizes, int n_in,
                              void* d_out, int out_size, void* d_ws, size_t ws_size,
                              hipStream_t stream) {
    const float* x     = (const float*)d_in[0];
    const float* bias  = (const float*)d_in[4];
    const float* wih_f = (const float*)d_in[5];
    const float* whh_f = (const float*)d_in[6];
    const float* bih_f = (const float*)d_in[7];
    const float* bhh_f = (const float*)d_in[8];
    const float* wih_b = (const float*)d_in[9];
    const float* whh_b = (const float*)d_in[10];
    const float* bih_b = (const float*)d_in[11];
    const float* bhh_b = (const float*)d_in[12];
    float* out = (float*)d_out;

    // Workspace layout (total 426,471,424 B ~= 406.7 MiB)
    char* ws = (char*)d_ws;
    __hip_bfloat16* msg = (__hip_bfloat16*)(ws);                    //  62,914,560 B
    __hip_bfloat16* wih = (__hip_bfloat16*)(ws + 62914560LL);       //   1,310,720 B
    __hip_bfloat16* whh = (__hip_bfloat16*)(ws + 64225280LL);       //   1,167,360 B
    float*          bih = (float*)         (ws + 65392640LL);       //       8,192 B
    float*          h0  = (float*)         (ws + 65400832LL);       //   2,457,600 B
    __hip_bfloat16* xp  = (__hip_bfloat16*)(ws + 67858432LL);       // 358,612,992 B

    hipLaunchKernelGGL(prep_weights, dim3((2*GW*KP + 2*GP*KP + 2*GW + 255) / 256), dim3(256), 0, stream,
                       wih_f, whh_f, bih_f, wih_b, whh_b, bih_b, wih, whh, bih);
    hipLaunchKernelGGL(prep_msg, dim3((NTOK * KP + 255) / 256), dim3(256), 0, stream, x, bias, msg);
    hipLaunchKernelGGL(h0_kernel, dim3(BM), dim3(256), 0, stream, x, h0);
    hipLaunchKernelGGL(xp_gemm, dim3(NTOK / 128, GW / 128, 2), dim3(256), 0, stream, msg, wih, bih, xp);
    hipLaunchKernelGGL(gru_kernel, dim3(BM / MOLW, 2), dim3(WGT), 0, stream, whh, bhh_f, bhh_b, xp, h0, out);
}

// Round 3
// 1609.897 us; speedup vs baseline: 1.2495x; 1.0766x over previous
//
#include <hip/hip_runtime.h>
#include <hip/hip_bf16.h>

// Problem constants (fixed by setup_inputs)
#define H    300
#define KP   320            // K padded to multiple of 32
#define BM   2048           // num molecules
#define SEG  48
#define NTOK (BM*SEG)       // 98304
#define G    900            // 3*H
#define GP   912            // hp width: 57*16
#define NT   57             // GP/16
#define GW   1024           // wih row-pad: 8*128 (B-operand tiles)
#define XPW  912            // xp row stride (cols >= 900 never read; 912 keeps 4B align)
#define MOLW 16             // molecules per recurrent workgroup
#define WGT  1024           // gru workgroup threads (16 waves -> 4 waves/SIMD, 1 WG/CU)
#define NPAIR (MOLW*150)    // bf16-pairs of gate state per wg = 2400
#define PIT  3              // pointwise iters: ceil(NPAIR/WGT)
#define BKX  64             // xp_gemm K-step (128B rows -> 8-chunk XOR swizzle, conflict-free)

typedef __attribute__((ext_vector_type(8))) short short8;
typedef __attribute__((ext_vector_type(4))) float f32x4;

__device__ __forceinline__ float lo16(unsigned u) { return __uint_as_float(u << 16); }
__device__ __forceinline__ float hi16(unsigned u) { return __uint_as_float(u & 0xffff0000u); }
__device__ __forceinline__ unsigned short bfb(float f) {
    __hip_bfloat16 b = __float2bfloat16(f);
    return *(unsigned short*)&b;
}
__device__ __forceinline__ void gload16(const void* g, void* l) {
    __builtin_amdgcn_global_load_lds((const __attribute__((address_space(1))) unsigned*)g,
                                     (__attribute__((address_space(3))) unsigned*)l, 16, 0, 0);
}

// ---------------- prep: weights -> padded bf16, biases -> padded f32 ----------------
__global__ void prep_weights(const float* wih_f, const float* whh_f, const float* bih_f,
                             const float* wih_b, const float* whh_b, const float* bih_b,
                             __hip_bfloat16* wih, __hip_bfloat16* whh, float* bih) {
    int idx = blockIdx.x * 256 + threadIdx.x;
    const int wih_n = 2 * GW * KP;
    const int whh_n = 2 * GP * KP;
    if (idx < wih_n) {
        int d = idx / (GW * KP);
        int r = (idx / KP) % GW;
        int k = idx % KP;
        const float* src = d ? wih_b : wih_f;
        float v = (r < G && k < H) ? src[r * H + k] : 0.f;
        wih[idx] = __float2bfloat16(v);
        return;
    }
    idx -= wih_n;
    if (idx < whh_n) {
        int d = idx / (GP * KP);
        int r = (idx / KP) % GP;
        int k = idx % KP;
        const float* src = d ? whh_b : whh_f;
        float v = (r < G && k < H) ? src[r * H + k] : 0.f;
        whh[idx] = __float2bfloat16(v);
        return;
    }
    idx -= whh_n;
    if (idx < 2 * GW) {
        int d = idx / GW;
        int r = idx % GW;
        const float* src = d ? bih_b : bih_f;
        bih[idx] = (r < G) ? src[r] : 0.f;
    }
}

// ---------------- prep: message = bf16(relu(x + bias)), K-padded ----------------
__global__ void prep_msg(const float* x, const float* bias, __hip_bfloat16* msg) {
    int idx = blockIdx.x * 256 + threadIdx.x;      // over NTOK*KP = 31,457,280
    if (idx >= NTOK * KP) return;
    int i = idx / KP, k = idx % KP;
    float v = 0.f;
    if (k < H) {
        v = x[i * H + k] + bias[k];
        v = v > 0.f ? v : 0.f;
    }
    msg[idx] = __float2bfloat16(v);
}

// ---------------- prep: h0 = segment_max(x) ----------------
__global__ void h0_kernel(const float* x, float* h0) {
    int m = blockIdx.x;
    for (int c = threadIdx.x; c < H; c += blockDim.x) {
        const float* base = x + (long long)m * SEG * H + c;
        float v = -INFINITY;
        for (int t = 0; t < SEG; t++) v = fmaxf(v, base[t * H]);
        h0[m * H + c] = v;
    }
}

// ---------------- xp = msg @ w_ih^T + b_ih  (m97-style: global_load_lds staging, 128x128 tile) ----------------
// LDS tiles [128][64] bf16 (128B rows). Staged linear-dest via global_load_lds with XOR-swizzled
// per-lane SOURCE chunks (chunk' = chunk ^ (row&7)); fragment ds_read applies the same XOR ->
// 8 bank-quads, 2 lanes each: conflict-free (rule #21: swizzle both sides or neither).
__global__ __launch_bounds__(256) void xp_gemm(const __hip_bfloat16* msg, const __hip_bfloat16* wih,
                                               const float* bih, __hip_bfloat16* xp) {
    int d = blockIdx.z;
    const __hip_bfloat16* A  = msg;
    const __hip_bfloat16* Bw = wih + d * GW * KP;
    const float* bi = bih + d * GW;
    __hip_bfloat16* out = xp + (long long)d * NTOK * XPW;

    __shared__ __hip_bfloat16 sA[128 * BKX];   // 16 KB
    __shared__ __hip_bfloat16 sB[128 * BKX];   // 16 KB
    const short* sAs = (const short*)sA;
    const short* sBs = (const short*)sB;

    int tid = threadIdx.x;
    int lane = tid & 63, wid = tid >> 6;
    int l15 = lane & 15, quad = lane >> 4;
    int mblk = blockIdx.x * 128, nblk = blockIdx.y * 128;
    int mbase = (wid >> 1) * 64, nbase = (wid & 1) * 64;

    // staging geometry (kc-invariant): wave w, inst j covers LDS chunks (w*4+j)*64 + lane
    int srow = wid * 32 + (lane >> 3);          // local row at j=0 (rows += 8 per j)
    int scc  = (lane & 7) ^ (srow & 7);         // swizzled source chunk-in-row
    const short* gA0 = (const short*)A  + (long long)(mblk + srow) * KP + scc * 8;
    const short* gB0 = (const short*)Bw + (long long)(nblk + srow) * KP + scc * 8;
    int xsw = (l15 & 7) << 3;                   // read-side XOR (shorts)

    f32x4 acc[4][4] = {};
    for (int kc = 0; kc < KP / BKX; kc++) {
#pragma unroll
        for (int j = 0; j < 4; j++)
            gload16(gA0 + (long long)j * 8 * KP + kc * BKX, (char*)sA + (wid * 4 + j) * 1024);
#pragma unroll
        for (int j = 0; j < 4; j++)
            gload16(gB0 + (long long)j * 8 * KP + kc * BKX, (char*)sB + (wid * 4 + j) * 1024);
        __syncthreads();   // compiler drains vmcnt before s_barrier -> LDS tiles ready

        short8 af[4][2], bf[4][2];
#pragma unroll
        for (int i = 0; i < 4; i++)
#pragma unroll
            for (int kh = 0; kh < 2; kh++)
                af[i][kh] = *(const short8*)(sAs + (mbase + i * 16 + l15) * BKX + ((kh * 32 + quad * 8) ^ xsw));
#pragma unroll
        for (int j = 0; j < 4; j++)
#pragma unroll
            for (int kh = 0; kh < 2; kh++)
                bf[j][kh] = *(const short8*)(sBs + (nbase + j * 16 + l15) * BKX + ((kh * 32 + quad * 8) ^ xsw));
#pragma unroll
        for (int i = 0; i < 4; i++)
#pragma unroll
            for (int j = 0; j < 4; j++) {
                acc[i][j] = __builtin_amdgcn_mfma_f32_16x16x32_bf16(af[i][0], bf[j][0], acc[i][j], 0, 0, 0);
                acc[i][j] = __builtin_amdgcn_mfma_f32_16x16x32_bf16(af[i][1], bf[j][1], acc[i][j], 0, 0, 0);
            }
        __syncthreads();   // before next kc overwrites LDS
    }

#pragma unroll
    for (int i = 0; i < 4; i++)
#pragma unroll
        for (int j = 0; j < 4; j++) {
            int col = nblk + nbase + j * 16 + l15;
            if (col < XPW) {
                float bv = bi[col];
#pragma unroll
                for (int r = 0; r < 4; r++) {
                    int row = mblk + mbase + i * 16 + quad * 4 + r;
                    out[(long long)row * XPW + col] = __float2bfloat16(acc[i][j][r] + bv);
                }
            }
        }
}

// ---------------- persistent bidirectional GRU over 48 steps ----------------
// grid (128, 2) = 256 WGs x 1024 thr = 16 waves -> 1 WG/CU, 4 waves/SIMD.
// This round: kk-outer GEMM with depth-3 B-register pipeline (MLP ~12 loads in flight vs ~2),
// A-fragments re-read from LDS (2-slot) to free 32 VGPRs, and xp prefetch moved AFTER the
// b-load issues and retargeted to step t+1 (vmcnt retires in order -> HBM xp loads at the
// FIFO head were blocking every b-load wait).
__global__ __launch_bounds__(WGT, 4) void gru_kernel(const __hip_bfloat16* whh_all, const float* bhh_f,
                                                     const float* bhh_b, const __hip_bfloat16* xp,
                                                     const float* h0, float* out) {
    int grp = blockIdx.x;      // molecule group, 0..127
    int d   = blockIdx.y;      // direction
    const short* Ws = (const short*)(whh_all + d * GP * KP);
    const float* bhh = d ? bhh_b : bhh_f;
    const __hip_bfloat16* xpd = xp + (long long)d * NTOK * XPW;

    int tid = threadIdx.x;
    int lane = tid & 63, wid = tid >> 6;           // wid 0..15
    int l15 = lane & 15, quad = lane >> 4;

    __shared__ __hip_bfloat16 hB[MOLW * 328];      // 10,496 B  bf16 h (A-operand), stride 328
    __shared__ __hip_bfloat16 hp[MOLW * GP];       // 29,184 B  recurrent projections (+b_hh)
    const short* hBs = (const short*)hB;

    int mol0 = grp * MOLW;

    // ---- zero hB (incl. K-pad cols 300..327) ----
    for (int e = tid; e < MOLW * 328; e += WGT) hB[e] = __float2bfloat16(0.f);

    // ---- per-wave B tiles: nt = wid + 16k, k<4; 4th tile clamped to tile0 for waves 9..15
    //      (duplicate loads L1-hit; acc[3] computed but never stored) ----
    const short* bpp[4];
    float bvw[4];
#pragma unroll
    for (int k = 0; k < 4; k++) {
        int nt = wid + 16 * k;
        int ntc = (nt < NT) ? nt : wid;
        bpp[k] = Ws + (ntc * 16 + l15) * KP;
        int gc = nt * 16 + l15;
        bvw[k] = (nt < NT && gc < G) ? bhh[gc] : 0.f;
    }

    // ---- pointwise element geometry (t-invariant) ----
    int m_[PIT], c_[PIT], xoff[PIT];
#pragma unroll
    for (int i = 0; i < PIT; i++) {
        int e2 = tid + i * WGT;
        int e2c = (e2 < NPAIR) ? e2 : 0;
        m_[i] = e2c / 150; c_[i] = 2 * (e2c % 150);
        xoff[i] = (mol0 + m_[i]) * SEG * XPW + c_[i];
    }
    __syncthreads();   // hB zeros visible before pair-writes below

    // ---- init h state: registers (gate-thread ownership) + hB bf16 copy ----
    float hv0[PIT], hv1[PIT];
#pragma unroll
    for (int i = 0; i < PIT; i++) {
        int e2 = tid + i * WGT;
        if (e2 < NPAIR) {
            float2 hh = *(const float2*)(h0 + (size_t)(mol0 + m_[i]) * H + c_[i]);
            hv0[i] = hh.x; hv1[i] = hh.y;
            unsigned pack = ((unsigned)bfb(hh.y) << 16) | bfb(hh.x);
            *(unsigned*)(&hB[m_[i] * 328 + c_[i]]) = pack;
        }
    }
    __syncthreads();

    // ---- prologue: xp prefetch for step 0 ----
    unsigned pcr[PIT], pcz[PIT], pcn[PIT];
    {
        int tt0 = d ? (SEG - 1) : 0;
#pragma unroll
        for (int i = 0; i < PIT; i++) {
            if (tid + i * WGT < NPAIR) {
                const __hip_bfloat16* xr = xpd + xoff[i] + tt0 * XPW;
                pcr[i] = *(const unsigned*)(xr);
                pcz[i] = *(const unsigned*)(xr + 300);
                pcn[i] = *(const unsigned*)(xr + 600);
            }
        }
    }

    for (int t = 0; t < SEG; t++) {
        int tt = d ? (SEG - 1 - t) : t;

        // ---- GEMM: hp = h @ w_hh^T + b_hh  (kk-outer, depth-3 B pipeline) ----
        f32x4 acc[4] = {};
        short8 bq[3][4];
        short8 aq[2];
#pragma unroll
        for (int k = 0; k < 4; k++) {
            bq[0][k] = *(const short8*)(bpp[k] + 0 * 32 + quad * 8);
            bq[1][k] = *(const short8*)(bpp[k] + 1 * 32 + quad * 8);
            bq[2][k] = *(const short8*)(bpp[k] + 2 * 32 + quad * 8);
        }
        aq[0] = *(const short8*)(hBs + l15 * 328 + 0 * 32 + quad * 8);
        aq[1] = *(const short8*)(hBs + l15 * 328 + 1 * 32 + quad * 8);
#pragma unroll
        for (int kk = 0; kk < 10; kk++) {
#pragma unroll
            for (int k = 0; k < 4; k++)
                acc[k] = __builtin_amdgcn_mfma_f32_16x16x32_bf16(aq[kk & 1], bq[kk % 3][k], acc[k], 0, 0, 0);
            if (kk < 7) {
#pragma unroll
                for (int k = 0; k < 4; k++)
                    bq[kk % 3][k] = *(const short8*)(bpp[k] + (kk + 3) * 32 + quad * 8);
            }
            if (kk < 8)
                aq[kk & 1] = *(const short8*)(hBs + l15 * 328 + (kk + 2) * 32 + quad * 8);
        }

        // ---- issue NEXT step's xp prefetch (newest in vmcnt FIFO -> never blocks b-waits;
        //      consumed next step's pointwise: full phase of latency hiding) ----
        unsigned pnr[PIT] = {0}, pnz[PIT] = {0}, pnn[PIT] = {0};
        if (t + 1 < SEG) {
            int tn = d ? (SEG - 2 - t) : (t + 1);
#pragma unroll
            for (int i = 0; i < PIT; i++) {
                if (tid + i * WGT < NPAIR) {
                    const __hip_bfloat16* xr = xpd + xoff[i] + tn * XPW;
                    pnr[i] = *(const unsigned*)(xr);
                    pnz[i] = *(const unsigned*)(xr + 300);
                    pnn[i] = *(const unsigned*)(xr + 600);
                }
            }
        }

        // ---- hp stores ----
#pragma unroll
        for (int k = 0; k < 4; k++) {
            int nt = wid + 16 * k;
            if (nt < NT) {
                int gcol = nt * 16 + l15;
#pragma unroll
                for (int r = 0; r < 4; r++)
                    hp[(quad * 4 + r) * GP + gcol] = __float2bfloat16(acc[k][r] + bvw[k]);
            }
        }
        __syncthreads();

        // ---- pointwise GRU gates (fp32, 2 elems/thread/iter) ----
#pragma unroll
        for (int i = 0; i < PIT; i++) {
            int e2 = tid + i * WGT;
            if (e2 < NPAIR) {
                int m = m_[i], c = c_[i];
                unsigned hr2 = *(const unsigned*)(&hp[m * GP + c]);
                unsigned hz2 = *(const unsigned*)(&hp[m * GP + c + 300]);
                unsigned hn2 = *(const unsigned*)(&hp[m * GP + c + 600]);

                float xr0 = lo16(pcr[i]), xr1 = hi16(pcr[i]);
                float xz0 = lo16(pcz[i]), xz1 = hi16(pcz[i]);
                float xn0 = lo16(pcn[i]), xn1 = hi16(pcn[i]);
                float hr0 = lo16(hr2),  hr1 = hi16(hr2);
                float hz0 = lo16(hz2),  hz1 = hi16(hz2);
                float hn0 = lo16(hn2),  hn1 = hi16(hn2);

                float rg0 = 1.f / (1.f + __expf(-(xr0 + hr0)));
                float rg1 = 1.f / (1.f + __expf(-(xr1 + hr1)));
                float zg0 = 1.f / (1.f + __expf(-(xz0 + hz0)));
                float zg1 = 1.f / (1.f + __expf(-(xz1 + hz1)));
                float ni0 = xn0 + rg0 * hn0;
                float ni1 = xn1 + rg1 * hn1;
                float ng0 = 1.f - 2.f / (__expf(2.f * ni0) + 1.f);
                float ng1 = 1.f - 2.f / (__expf(2.f * ni1) + 1.f);
                float h0n = (1.f - zg0) * ng0 + zg0 * hv0[i];
                float h1n = (1.f - zg1) * ng1 + zg1 * hv1[i];
                hv0[i] = h0n; hv1[i] = h1n;

                unsigned pack = ((unsigned)bfb(h1n) << 16) | bfb(h0n);
                *(unsigned*)(&hB[m * 328 + c]) = pack;

                long long tok = (long long)(mol0 + m) * SEG + tt;
                *(float2*)(out + tok * 600 + d * 300 + c) = make_float2(h0n, h1n);
            }
        }
        // rotate prefetch regs
#pragma unroll
        for (int i = 0; i < PIT; i++) { pcr[i] = pnr[i]; pcz[i] = pnz[i]; pcn[i] = pnn[i]; }
        __syncthreads();
    }
}

extern "C" void kernel_launch(void* const* d_in, const int* in_sizes, int n_in,
                              void* d_out, int out_size, void* d_ws, size_t ws_size,
                              hipStream_t stream) {
    const float* x     = (const float*)d_in[0];
    const float* bias  = (const float*)d_in[4];
    const float* wih_f = (const float*)d_in[5];
    const float* whh_f = (const float*)d_in[6];
    const float* bih_f = (const float*)d_in[7];
    const float* bhh_f = (const float*)d_in[8];
    const float* wih_b = (const float*)d_in[9];
    const float* whh_b = (const float*)d_in[10];
    const float* bih_b = (const float*)d_in[11];
    const float* bhh_b = (const float*)d_in[12];
    float* out = (float*)d_out;

    // Workspace layout (total 426,471,424 B ~= 406.7 MiB)
    char* ws = (char*)d_ws;
    __hip_bfloat16* msg = (__hip_bfloat16*)(ws);                    //  62,914,560 B
    __hip_bfloat16* wih = (__hip_bfloat16*)(ws + 62914560LL);       //   1,310,720 B
    __hip_bfloat16* whh = (__hip_bfloat16*)(ws + 64225280LL);       //   1,167,360 B
    float*          bih = (float*)         (ws + 65392640LL);       //       8,192 B
    float*          h0  = (float*)         (ws + 65400832LL);       //   2,457,600 B
    __hip_bfloat16* xp  = (__hip_bfloat16*)(ws + 67858432LL);       // 358,612,992 B

    hipLaunchKernelGGL(prep_weights, dim3((2*GW*KP + 2*GP*KP + 2*GW + 255) / 256), dim3(256), 0, stream,
                       wih_f, whh_f, bih_f, wih_b, whh_b, bih_b, wih, whh, bih);
    hipLaunchKernelGGL(prep_msg, dim3((NTOK * KP + 255) / 256), dim3(256), 0, stream, x, bias, msg);
    hipLaunchKernelGGL(h0_kernel, dim3(BM), dim3(256), 0, stream, x, h0);
    hipLaunchKernelGGL(xp_gemm, dim3(NTOK / 128, GW / 128, 2), dim3(256), 0, stream, msg, wih, bih, xp);
    hipLaunchKernelGGL(gru_kernel, dim3(BM / MOLW, 2), dim3(WGT), 0, stream, whh, bhh_f, bhh_b, xp, h0, out);
}